// Round 3
// baseline (178.815 us; speedup 1.0000x reference)
//
#include <hip/hip_runtime.h>
#include <math.h>

#define SEQ 512
#define HID 256
#define KDIM 256
#define NH 8
#define DH 32
#define PI_F 3.14159265358979323846f
#define SCALE_F 0.17677669529663687f  /* 1/sqrt(32) */
#define LOG2E_F 1.4426950408889634f

#define ROWS 8
#define KCH 32

// ws layout (float offsets):
#define OFF_OMEGA 0
#define OFF_AMP   131072
#define OFF_PHASE 262144
#define OFF_VT    393216   /* v transposed: [HID][SEQ] */
#define OFF_CTX   524288   /* context [SEQ][HID] */

// ---------------- QKV projection + activations ----------------
// out[r,c] = sum_k x[r,k] * W[c,k] + b[c].
// Block 256 threads = one column each, ROWS rows per block.
// x values are wave-uniform -> s_load; W staged k-major in LDS (stride 257,
// conflict-free per-lane ds_read_b32, 1 read feeds 8 FMAs).
__global__ __launch_bounds__(256) void proj_qkv(
    const float* __restrict__ x,
    const float* __restrict__ wq, const float* __restrict__ bq,
    const float* __restrict__ wk, const float* __restrict__ bk,
    const float* __restrict__ wv, const float* __restrict__ bv,
    float* __restrict__ ws)
{
    const int which = blockIdx.y;
    const float* W = (which == 0) ? wq : (which == 1) ? wk : wv;
    const float* B = (which == 0) ? bq : (which == 1) ? bk : bv;
    const int r0 = blockIdx.x * ROWS;
    const int c = threadIdx.x;

    __shared__ float wls[KCH][257];

    float acc[ROWS];
#pragma unroll
    for (int r = 0; r < ROWS; r++) acc[r] = 0.f;

    for (int kb = 0; kb < KDIM; kb += KCH) {
        // stage W[0..255][kb..kb+KCH) into wls[k][c], coalesced float4 loads
#pragma unroll
        for (int it = 0; it < (256 * KCH / 4) / 256; it++) {
            int idx = threadIdx.x + it * 256;   // 0..2047
            int cc = idx >> 3;
            int ff = idx & 7;
            float4 w4 = *(const float4*)(W + cc * KDIM + kb + 4 * ff);
            wls[4 * ff + 0][cc] = w4.x;
            wls[4 * ff + 1][cc] = w4.y;
            wls[4 * ff + 2][cc] = w4.z;
            wls[4 * ff + 3][cc] = w4.w;
        }
        __syncthreads();
#pragma unroll
        for (int k = 0; k < KCH; k += 4) {
            float w0 = wls[k + 0][c];
            float w1 = wls[k + 1][c];
            float w2 = wls[k + 2][c];
            float w3 = wls[k + 3][c];
#pragma unroll
            for (int r = 0; r < ROWS; r++) {
                float4 x4 = *(const float4*)(x + (r0 + r) * KDIM + kb + k); // uniform -> s_load
                acc[r] = fmaf(x4.x, w0, acc[r]);
                acc[r] = fmaf(x4.y, w1, acc[r]);
                acc[r] = fmaf(x4.z, w2, acc[r]);
                acc[r] = fmaf(x4.w, w3, acc[r]);
            }
        }
        __syncthreads();
    }

    const float bb = B[c];
#pragma unroll
    for (int r = 0; r < ROWS; r++) {
        float val = acc[r] + bb;
        int row = r0 + r;
        int o = row * HID + c;
        if (which == 0) {
            ws[OFF_OMEGA + o] = PI_F / (1.f + expf(-val));      // omega
        } else if (which == 1) {
            ws[OFF_AMP + o] = 1.f / (1.f + expf(-val));         // amplitude
        } else {
            ws[OFF_PHASE + o] = PI_F * tanhf(val);              // phase
            ws[OFF_VT + c * SEQ + row] = val;                   // v transposed
        }
    }
}

// ---------------- wave-interference attention ----------------
// thread = (i_local = tid>>5, d = tid&31); grid (SEQ/8, NH).
// exp(amp*SCALE*cos(w*(i-j)+ph)) via 4 independent rotation chains
// (j = k mod 4, step angle 4w) with amp*SCALE*log2e folded into the state,
// so the inner loop is 4 FMA-rot + 1 v_exp per j. v read as float4 from vT.
__global__ __launch_bounds__(256) void wave_attn(const float* __restrict__ ws,
                                                 float* __restrict__ ctx)
{
    const int h  = blockIdx.y;
    const int il = threadIdx.x >> 5;
    const int d  = threadIdx.x & 31;
    const int i  = blockIdx.x * 8 + il;
    const int col = h * DH + d;

    const float w  = ws[OFF_OMEGA + i * HID + col];
    const float aL = ws[OFF_AMP + i * HID + col] * (SCALE_F * LOG2E_F);
    const float ph = ws[OFF_PHASE + i * HID + col];

    const float4* vt4 = (const float4*)(ws + OFF_VT + col * SEQ);

    float p[4], q[4], den[4], num[4];
#pragma unroll
    for (int k = 0; k < 4; k++) {
        float th = w * (float)(i - k) + ph;   // theta at j = k
        p[k] = aL * cosf(th);                 // precise libm init
        q[k] = aL * sinf(th);
        den[k] = 0.f;
        num[k] = 0.f;
    }
    const float cd = cosf(4.f * w);           // rotation by -4w per step
    const float sd = sinf(4.f * w);

#pragma unroll 4
    for (int t = 0; t < SEQ / 4; t++) {
        float4 v4 = vt4[t];
        float e0 = __builtin_amdgcn_exp2f(p[0]);
        float e1 = __builtin_amdgcn_exp2f(p[1]);
        float e2 = __builtin_amdgcn_exp2f(p[2]);
        float e3 = __builtin_amdgcn_exp2f(p[3]);
        den[0] += e0; den[1] += e1; den[2] += e2; den[3] += e3;
        num[0] = fmaf(e0, v4.x, num[0]);
        num[1] = fmaf(e1, v4.y, num[1]);
        num[2] = fmaf(e2, v4.z, num[2]);
        num[3] = fmaf(e3, v4.w, num[3]);
#pragma unroll
        for (int k = 0; k < 4; k++) {
            float np = p[k] * cd + q[k] * sd;   // cos(th-4w) scaled
            float nq = q[k] * cd - p[k] * sd;   // sin(th-4w) scaled
            p[k] = np;
            q[k] = nq;
        }
    }
    float denom = (den[0] + den[1]) + (den[2] + den[3]);
    float numer = (num[0] + num[1]) + (num[2] + num[3]);
    ctx[i * HID + col] = numer / denom;   // ctx pointer already offset at launch
}

// ---------------- output projection ----------------
__global__ __launch_bounds__(256) void proj_out(
    const float* __restrict__ ctx, const float* __restrict__ wo,
    const float* __restrict__ bo, float* __restrict__ out)
{
    const int r0 = blockIdx.x * ROWS;
    const int c = threadIdx.x;

    __shared__ float wls[KCH][257];

    float acc[ROWS];
#pragma unroll
    for (int r = 0; r < ROWS; r++) acc[r] = 0.f;

    for (int kb = 0; kb < KDIM; kb += KCH) {
#pragma unroll
        for (int it = 0; it < (256 * KCH / 4) / 256; it++) {
            int idx = threadIdx.x + it * 256;
            int cc = idx >> 3;
            int ff = idx & 7;
            float4 w4 = *(const float4*)(wo + cc * KDIM + kb + 4 * ff);
            wls[4 * ff + 0][cc] = w4.x;
            wls[4 * ff + 1][cc] = w4.y;
            wls[4 * ff + 2][cc] = w4.z;
            wls[4 * ff + 3][cc] = w4.w;
        }
        __syncthreads();
#pragma unroll
        for (int k = 0; k < KCH; k += 4) {
            float w0 = wls[k + 0][c];
            float w1 = wls[k + 1][c];
            float w2 = wls[k + 2][c];
            float w3 = wls[k + 3][c];
#pragma unroll
            for (int r = 0; r < ROWS; r++) {
                float4 x4 = *(const float4*)(ctx + (r0 + r) * KDIM + kb + k);
                acc[r] = fmaf(x4.x, w0, acc[r]);
                acc[r] = fmaf(x4.y, w1, acc[r]);
                acc[r] = fmaf(x4.z, w2, acc[r]);
                acc[r] = fmaf(x4.w, w3, acc[r]);
            }
        }
        __syncthreads();
    }

    const float bb = bo[c];
#pragma unroll
    for (int r = 0; r < ROWS; r++) {
        out[(r0 + r) * HID + c] = acc[r] + bb;
    }
}

extern "C" void kernel_launch(void* const* d_in, const int* in_sizes, int n_in,
                              void* d_out, int out_size, void* d_ws, size_t ws_size,
                              hipStream_t stream) {
    const float* x  = (const float*)d_in[0];
    const float* wq = (const float*)d_in[1];
    const float* bq = (const float*)d_in[2];
    const float* wk = (const float*)d_in[3];
    const float* bk = (const float*)d_in[4];
    const float* wv = (const float*)d_in[5];
    const float* bv = (const float*)d_in[6];
    const float* wo = (const float*)d_in[7];
    const float* bo = (const float*)d_in[8];

    float* ws  = (float*)d_ws;
    float* ctx = ws + OFF_CTX;

    hipLaunchKernelGGL(proj_qkv, dim3(SEQ / ROWS, 3), dim3(256), 0, stream,
                       x, wq, bq, wk, bk, wv, bv, ws);
    hipLaunchKernelGGL(wave_attn, dim3(SEQ / 8, NH), dim3(256), 0, stream,
                       ws, ctx);
    hipLaunchKernelGGL(proj_out, dim3(SEQ / ROWS), dim3(256), 0, stream,
                       ctx, wo, bo, (float*)d_out);
}

// Round 4
// 107.442 us; speedup vs baseline: 1.6643x; 1.6643x over previous
//
#include <hip/hip_runtime.h>
#include <math.h>

#define SEQ 512
#define HID 256
#define NH 8
#define DH 32
#define PI_F 3.14159265358979323846f
#define SCALE_F 0.17677669529663687f  /* 1/sqrt(32) */
#define LOG2E_F 1.4426950408889634f

// ws layout (float offsets)
#define OFF_OMEGA 0
#define OFF_AMP   131072
#define OFF_PHASE 262144
#define OFF_V     393216
#define OFF_CTX   524288
#define OFF_PQKV  655360            /* 12 slices x 131072 */
#define OFF_POUT  2228224           /* 4 slices x 131072 */

// ---------------- 64x64 tile, 64-k-slice GEMM partial ----------------
// part[r][c] = sum_{k in slice} A[r][k] * W[c][k]
// grid.x = 128 (rt:8 x ct:4 x ks:4), grid.y selects W (QKV) or 1 (out).
// All global loads coalesced (lanes along k). LDS: A natural [r][k] stride 68
// (2-way reads/writes only), W transposed [k][c^swz] stride 64 with XOR-4
// swizzle so both the transpose-write and the b128 compute-read are <=2-way.
__global__ __launch_bounds__(256) void gemm_slice(
    const float* __restrict__ A,
    const float* __restrict__ W0, const float* __restrict__ W1,
    const float* __restrict__ W2, float* __restrict__ part)
{
    const int which = blockIdx.y;
    const float* W = (which == 0) ? W0 : (which == 1) ? W1 : W2;
    const int bx = blockIdx.x;
    const int ks = bx & 3;
    const int ct = (bx >> 2) & 3;
    const int rt = bx >> 4;
    const int r0 = rt * 64, c0 = ct * 64, k0 = ks * 64;

    __shared__ float xs[64 * 68];
    __shared__ float wts[64 * 64];

    const int tid = threadIdx.x;
#pragma unroll
    for (int it = 0; it < 4; it++) {
        int idx = tid + it * 256;
        int rr = idx >> 4, f4 = idx & 15;          // 16 lanes: same rr, f4=0..15
        float4 av = *(const float4*)(A + (r0 + rr) * HID + k0 + 4 * f4);
        *(float4*)&xs[rr * 68 + 4 * f4] = av;      // b128 write, 2-way banks
        float4 wv = *(const float4*)(W + (c0 + rr) * HID + k0 + 4 * f4);
        int cw = rr ^ ((f4 & 7) << 2);             // swizzle on col index
        wts[(4 * f4 + 0) * 64 + cw] = wv.x;
        wts[(4 * f4 + 1) * 64 + cw] = wv.y;
        wts[(4 * f4 + 2) * 64 + cw] = wv.z;
        wts[(4 * f4 + 3) * 64 + cw] = wv.w;
    }
    __syncthreads();

    const int rg = tid >> 4, cg = tid & 15;
    float acc[4][4];
#pragma unroll
    for (int i = 0; i < 4; i++)
#pragma unroll
        for (int j = 0; j < 4; j++) acc[i][j] = 0.f;

#pragma unroll
    for (int g = 0; g < 16; g++) {
        float xfa[4][4], wfa[4][4];
#pragma unroll
        for (int i = 0; i < 4; i++) {
            float4 xv = *(const float4*)&xs[(4 * rg + i) * 68 + 4 * g];
            xfa[i][0] = xv.x; xfa[i][1] = xv.y; xfa[i][2] = xv.z; xfa[i][3] = xv.w;
        }
        const int sw = (g & 7) << 2;
#pragma unroll
        for (int m = 0; m < 4; m++) {
            float4 wv = *(const float4*)&wts[(4 * g + m) * 64 + ((4 * cg) ^ sw)];
            wfa[m][0] = wv.x; wfa[m][1] = wv.y; wfa[m][2] = wv.z; wfa[m][3] = wv.w;
        }
#pragma unroll
        for (int m = 0; m < 4; m++)
#pragma unroll
            for (int i = 0; i < 4; i++)
#pragma unroll
                for (int j = 0; j < 4; j++)
                    acc[i][j] = fmaf(xfa[i][m], wfa[m][j], acc[i][j]);
    }

    float* P = part + (size_t)(which * 4 + ks) * (SEQ * HID);
#pragma unroll
    for (int i = 0; i < 4; i++) {
        float4 o;
        o.x = acc[i][0]; o.y = acc[i][1]; o.z = acc[i][2]; o.w = acc[i][3];
        *(float4*)&P[(r0 + 4 * rg + i) * HID + c0 + 4 * cg] = o;
    }
}

// ---------------- reduce k-slices + bias + activations ----------------
__global__ __launch_bounds__(256) void reduce_qkv(
    const float* __restrict__ part,
    const float* __restrict__ bq, const float* __restrict__ bk,
    const float* __restrict__ bv, float* __restrict__ ws)
{
    const int which = blockIdx.y;
    const int r = blockIdx.x, c = threadIdx.x;
    const float* P = part + (size_t)which * 4 * (SEQ * HID) + r * HID + c;
    float s = (P[0] + P[SEQ * HID]) + (P[2 * SEQ * HID] + P[3 * SEQ * HID]);
    const int o = r * HID + c;
    if (which == 0) {
        s += bq[c];
        ws[OFF_OMEGA + o] = PI_F / (1.f + expf(-s));
    } else if (which == 1) {
        s += bk[c];
        ws[OFF_AMP + o] = 1.f / (1.f + expf(-s));
    } else {
        s += bv[c];
        ws[OFF_V + o] = s;
        ws[OFF_PHASE + o] = PI_F * tanhf(s);
    }
}

__global__ __launch_bounds__(256) void reduce_out(
    const float* __restrict__ part, const float* __restrict__ bo,
    float* __restrict__ out)
{
    const int r = blockIdx.x, c = threadIdx.x;
    const float* P = part + r * HID + c;
    float s = (P[0] + P[SEQ * HID]) + (P[2 * SEQ * HID] + P[3 * SEQ * HID]);
    out[r * HID + c] = s + bo[c];
}

// ---------------- wave-interference attention ----------------
// thread = (il = tid>>5, d = tid&31); grid (SEQ/8, NH). v in natural [j][col]
// layout -> one 128B txn per wave per j. Rotation recurrence (4 indep chains,
// step -4w) with amp*SCALE*log2e folded in; hw exp2 per j.
__global__ __launch_bounds__(256) void wave_attn(const float* __restrict__ ws,
                                                 float* __restrict__ ctx)
{
    const int h  = blockIdx.y;
    const int il = threadIdx.x >> 5;
    const int d  = threadIdx.x & 31;
    const int i  = blockIdx.x * 8 + il;
    const int col = h * DH + d;

    const float w  = ws[OFF_OMEGA + i * HID + col];
    const float aL = ws[OFF_AMP + i * HID + col] * (SCALE_F * LOG2E_F);
    const float ph = ws[OFF_PHASE + i * HID + col];
    const float* vcol = ws + OFF_V + col;

    float sw_, cw;
    sincosf(w, &sw_, &cw);
    float c2 = cw * cw - sw_ * sw_, s2 = 2.f * sw_ * cw;
    float c4 = c2 * c2 - s2 * s2,   s4 = 2.f * s2 * c2;

    float th0 = fmaf(w, (float)i, ph);      // angle at j=0
    float s0, cc0;
    sincosf(th0, &s0, &cc0);

    float pc[4], psn[4];
    pc[0] = cc0; psn[0] = s0;
#pragma unroll
    for (int k = 1; k < 4; k++) {           // rotate by -w per step
        float nc = pc[k - 1] * cw + psn[k - 1] * sw_;
        float ns = psn[k - 1] * cw - pc[k - 1] * sw_;
        pc[k] = nc; psn[k] = ns;
    }
    float p[4], q[4], den[4], num[4];
#pragma unroll
    for (int k = 0; k < 4; k++) {
        p[k] = aL * pc[k]; q[k] = aL * psn[k];
        den[k] = 0.f; num[k] = 0.f;
    }

#pragma unroll 4
    for (int t = 0; t < SEQ / 4; t++) {
        float v0 = vcol[(4 * t + 0) * HID];
        float v1 = vcol[(4 * t + 1) * HID];
        float v2v = vcol[(4 * t + 2) * HID];
        float v3 = vcol[(4 * t + 3) * HID];
        float e0 = __builtin_amdgcn_exp2f(p[0]);
        float e1 = __builtin_amdgcn_exp2f(p[1]);
        float e2 = __builtin_amdgcn_exp2f(p[2]);
        float e3 = __builtin_amdgcn_exp2f(p[3]);
        den[0] += e0; den[1] += e1; den[2] += e2; den[3] += e3;
        num[0] = fmaf(e0, v0, num[0]);
        num[1] = fmaf(e1, v1, num[1]);
        num[2] = fmaf(e2, v2v, num[2]);
        num[3] = fmaf(e3, v3, num[3]);
#pragma unroll
        for (int k = 0; k < 4; k++) {
            float np = p[k] * c4 + q[k] * s4;   // angle -= 4w
            float nq = q[k] * c4 - p[k] * s4;
            p[k] = np; q[k] = nq;
        }
    }
    float denom = (den[0] + den[1]) + (den[2] + den[3]);
    float numer = (num[0] + num[1]) + (num[2] + num[3]);
    ctx[i * HID + col] = numer / denom;
}

extern "C" void kernel_launch(void* const* d_in, const int* in_sizes, int n_in,
                              void* d_out, int out_size, void* d_ws, size_t ws_size,
                              hipStream_t stream) {
    const float* x  = (const float*)d_in[0];
    const float* wq = (const float*)d_in[1];
    const float* bq = (const float*)d_in[2];
    const float* wk = (const float*)d_in[3];
    const float* bk = (const float*)d_in[4];
    const float* wv = (const float*)d_in[5];
    const float* bv = (const float*)d_in[6];
    const float* wo = (const float*)d_in[7];
    const float* bo = (const float*)d_in[8];

    float* ws = (float*)d_ws;

    hipLaunchKernelGGL(gemm_slice, dim3(128, 3), dim3(256), 0, stream,
                       x, wq, wk, wv, ws + OFF_PQKV);
    hipLaunchKernelGGL(reduce_qkv, dim3(SEQ, 3), dim3(256), 0, stream,
                       ws + OFF_PQKV, bq, bk, bv, ws);
    hipLaunchKernelGGL(wave_attn, dim3(SEQ / 8, NH), dim3(256), 0, stream,
                       ws, ws + OFF_CTX);
    hipLaunchKernelGGL(gemm_slice, dim3(128, 1), dim3(256), 0, stream,
                       ws + OFF_CTX, wo, wo, wo, ws + OFF_POUT);
    hipLaunchKernelGGL(reduce_out, dim3(SEQ), dim3(256), 0, stream,
                       ws + OFF_POUT, bo, (float*)d_out);
}